// Round 7
// baseline (147.150 us; speedup 1.0000x reference)
//
#include <hip/hip_runtime.h>
#include <math.h>

#define N_NODES 1024
#define IN_F 512
#define N_HEADS 4
#define N_HID 32
#define OUT_F 128   // N_HEADS*N_HID
#define GF 256      // fused g row: [0..127]=g_l, [128..255]=g_r
#define NEG_SLOPE 0.2f

// ---------------- Kernel 0: pack adj into per-row bitmasks -----------------
// bits[i][w] bit k  <=>  adj[i][w*64+k] != 0.  1024 blocks x 256 thr.
__global__ __launch_bounds__(256) void gat_pack(
    const int* __restrict__ adj, unsigned long long* __restrict__ bits)
{
  const int i = blockIdx.x;
  const int t = threadIdx.x;
#pragma unroll
  for (int q = 0; q < 4; ++q) {
    const int j = q * 256 + t;
    const int a = adj[(size_t)i * N_NODES + j];
    const unsigned long long m = __ballot(a != 0);
    if ((t & 63) == 0) bits[i * 16 + (j >> 6)] = m;
  }
}

// ---------------- Kernel 1: LDS-tiled partial GEMM gpart[kc][row][c] -------
// grid 512 = (it 16 x ct 4 x kc 8), 256 thr. BM=BN=64, k-chunk 64, TK=16.
__global__ __launch_bounds__(256, 2) void gat_gemm(
    const float* __restrict__ hmat, const float* __restrict__ Wl,
    const float* __restrict__ Wr, float* __restrict__ gpart)
{
  const int b = blockIdx.x;
  const int kc = b & 7, ct = (b >> 3) & 3, it = b >> 5;
  const int i0 = it * 64, k0 = kc * 64, cb0 = ct * 64;
  const float* __restrict__ W = (cb0 < 128) ? (Wl + cb0) : (Wr + (cb0 - 128));

  __shared__ float As[16][68];
  __shared__ float Bs[16][64];

  const int tx = threadIdx.x & 15, ty = threadIdx.x >> 4;
  const int ar = threadIdx.x >> 2, ak = (threadIdx.x & 3) * 4;
  const int bk = threadIdx.x >> 4, bc = (threadIdx.x & 15) * 4;

  float4 acc0 = {0.f, 0.f, 0.f, 0.f}, acc1 = acc0, acc2 = acc0, acc3 = acc0;

  float4 av = *(const float4*)(hmat + (size_t)(i0 + ar) * IN_F + k0 + ak);
  float4 bv = *(const float4*)(W + (size_t)(k0 + bk) * OUT_F + bc);

  for (int t = 0; t < 64; t += 16) {
    __syncthreads();
    As[ak + 0][ar] = av.x; As[ak + 1][ar] = av.y;
    As[ak + 2][ar] = av.z; As[ak + 3][ar] = av.w;
    *(float4*)&Bs[bk][bc] = bv;
    __syncthreads();
    if (t < 48) {
      av = *(const float4*)(hmat + (size_t)(i0 + ar) * IN_F + k0 + t + 16 + ak);
      bv = *(const float4*)(W + (size_t)(k0 + t + 16 + bk) * OUT_F + bc);
    }
#pragma unroll
    for (int k = 0; k < 16; ++k) {
      const float4 a  = *(const float4*)&As[k][ty * 4];
      const float4 bb = *(const float4*)&Bs[k][tx * 4];
      acc0.x = fmaf(a.x, bb.x, acc0.x); acc0.y = fmaf(a.x, bb.y, acc0.y);
      acc0.z = fmaf(a.x, bb.z, acc0.z); acc0.w = fmaf(a.x, bb.w, acc0.w);
      acc1.x = fmaf(a.y, bb.x, acc1.x); acc1.y = fmaf(a.y, bb.y, acc1.y);
      acc1.z = fmaf(a.y, bb.z, acc1.z); acc1.w = fmaf(a.y, bb.w, acc1.w);
      acc2.x = fmaf(a.z, bb.x, acc2.x); acc2.y = fmaf(a.z, bb.y, acc2.y);
      acc2.z = fmaf(a.z, bb.z, acc2.z); acc2.w = fmaf(a.z, bb.w, acc2.w);
      acc3.x = fmaf(a.w, bb.x, acc3.x); acc3.y = fmaf(a.w, bb.y, acc3.y);
      acc3.z = fmaf(a.w, bb.z, acc3.z); acc3.w = fmaf(a.w, bb.w, acc3.w);
    }
  }
  const size_t rbase = (size_t)kc * N_NODES + i0 + ty * 4;
  const int cc = cb0 + tx * 4;
  *(float4*)(gpart + (rbase + 0) * GF + cc) = acc0;
  *(float4*)(gpart + (rbase + 1) * GF + cc) = acc1;
  *(float4*)(gpart + (rbase + 2) * GF + cc) = acc2;
  *(float4*)(gpart + (rbase + 3) * GF + cc) = acc3;
}

// ---------------- Kernel 2: g = sum partials; alpha/beta precompute --------
// alpha_h[j] = sum_f 0.6*aw[f]*gl[j,h,f]; beta_h[i] = same on gr.
__global__ __launch_bounds__(256) void gat_reduceWab(
    const float* __restrict__ gpart, const float* __restrict__ attn_w,
    float* __restrict__ g, float* __restrict__ abuf, float* __restrict__ bbuf)
{
  const int tid = threadIdx.x;
  const int l = tid & 63, r = tid >> 6;
  const int row = blockIdx.x * 4 + r;
  const size_t o = (size_t)row * GF + l * 4;
  float4 s = *(const float4*)(gpart + o);
#pragma unroll
  for (int c = 1; c < 8; ++c) {
    const float4 v = *(const float4*)(gpart + (size_t)c * (N_NODES * GF) + o);
    s.x += v.x; s.y += v.y; s.z += v.z; s.w += v.w;
  }
  *(float4*)(g + o) = s;
  const float4 a4 = *(const float4*)(attn_w + (l & 7) * 4);
  float d = 0.6f * (s.x * a4.x + s.y * a4.y + s.z * a4.z + s.w * a4.w);
  d += __shfl_xor(d, 1);
  d += __shfl_xor(d, 2);
  d += __shfl_xor(d, 4);
  if ((l & 7) == 0) {
    const int hq = l >> 3;  // 0-3 -> alpha (gl), 4-7 -> beta (gr)
    if (hq < 4) abuf[hq * N_NODES + row] = d;
    else        bbuf[(hq - 4) * N_NODES + row] = d;
  }
}

// ---------------- Kernel 3: fused score+softmax-num+aggregate --------------
// Thread = (i, head, feature-half): num[16]+gr_i[16]+c2[16] in regs (~100 VGPR).
// Wave = (1 head x 2 halves x 32 i) -> LDS reads are 2-address broadcasts.
// e = alpha[h][j] + beta[h][i] + (my half + shfl_xor-partner half) of
//     sum_f 0.4*aw[f]*|gl[j,f]+gr[i,f]|;  p = bit(i,j) ? exp(e) : 0.
// num[f] += p*gr[j][f]; den partial per (jc,h,i). No p materialization.
// grid 512 = (jc 16 x it 32): i-tile 32, j-chunk 64 (4 subtiles of 16).
__global__ __launch_bounds__(256, 2) void gat_fused(
    const float* __restrict__ g, const float* __restrict__ attn_w,
    const float* __restrict__ abuf, const float* __restrict__ bbuf,
    const unsigned long long* __restrict__ bits,
    float* __restrict__ num_part, float* __restrict__ den_part)
{
  __shared__ float T[32 * 132];  // j-tile [16][260] ; reused as numT [32][132]
  __shared__ float as_[4 * 17];

  const int b = blockIdx.x;
  const int jc = b & 15, it = b >> 4;
  const int i0 = it * 32, j0 = jc * 64;

  const int t = threadIdx.x;
  const int hh = t >> 6, half = (t >> 5) & 1, il = t & 31;
  const int i = i0 + il;
  const int fbase = hh * N_HID + half * 16;

  float4 gri[4], c2[4], num4[4];
#pragma unroll
  for (int q = 0; q < 4; ++q) {
    gri[q] = *(const float4*)(g + (size_t)i * GF + 128 + fbase + q * 4);
    const float4 a4 = *(const float4*)(attn_w + half * 16 + q * 4);
    c2[q] = make_float4(0.4f * a4.x, 0.4f * a4.y, 0.4f * a4.z, 0.4f * a4.w);
    num4[q] = make_float4(0.f, 0.f, 0.f, 0.f);
  }
  const float beta = bbuf[hh * N_NODES + i];
  const unsigned long long bm = bits[(size_t)i * 16 + jc];
  float den_t = 0.f;

  const int sr = t >> 4, sc = t & 15;  // staging: row, 16-float col group

  for (int ts = 0; ts < 4; ++ts) {
    __syncthreads();
    {
      const float* src = g + (size_t)(j0 + ts * 16 + sr) * GF + sc * 16;
      float* dst = &T[sr * 260 + sc * 16];
#pragma unroll
      for (int k = 0; k < 4; ++k)
        *(float4*)(dst + k * 4) = *(const float4*)(src + k * 4);
      if (t < 64)
        as_[(t >> 4) * 17 + (t & 15)] =
            abuf[(t >> 4) * N_NODES + j0 + ts * 16 + (t & 15)];
    }
    __syncthreads();
    const unsigned int w16 = (unsigned int)(bm >> (ts * 16)) & 0xFFFFu;
#pragma unroll
    for (int jj = 0; jj < 16; ++jj) {
      const float* row = &T[jj * 260];
      float part = 0.f;
      float4 grq[4];
#pragma unroll
      for (int q = 0; q < 4; ++q) {
        const float4 gl = *(const float4*)(row + fbase + q * 4);
        grq[q] = *(const float4*)(row + 128 + fbase + q * 4);
        float s;
        s = gl.x + gri[q].x; part = fmaf(c2[q].x, __builtin_fabsf(s), part);
        s = gl.y + gri[q].y; part = fmaf(c2[q].y, __builtin_fabsf(s), part);
        s = gl.z + gri[q].z; part = fmaf(c2[q].z, __builtin_fabsf(s), part);
        s = gl.w + gri[q].w; part = fmaf(c2[q].w, __builtin_fabsf(s), part);
      }
      const float full = part + __shfl_xor(part, 32);
      const float e = full + as_[hh * 17 + jj] + beta;
      const float p = ((w16 >> jj) & 1u) ? __expf(e) : 0.f;
      den_t += p;
#pragma unroll
      for (int q = 0; q < 4; ++q) {
        num4[q].x = fmaf(p, grq[q].x, num4[q].x);
        num4[q].y = fmaf(p, grq[q].y, num4[q].y);
        num4[q].z = fmaf(p, grq[q].z, num4[q].z);
        num4[q].w = fmaf(p, grq[q].w, num4[q].w);
      }
    }
  }

  if (half == 0)
    den_part[((size_t)jc * N_HEADS + hh) * N_NODES + i] = den_t;

  // transpose num through LDS for coalesced global writes
  __syncthreads();
#pragma unroll
  for (int q = 0; q < 4; ++q)
    *(float4*)&T[il * 132 + fbase + q * 4] = num4[q];
  __syncthreads();
  {
    const int r = t >> 3, cg = t & 7;
    float* dst = num_part + ((size_t)jc * N_NODES + i0 + r) * OUT_F + cg * 16;
    const float* srcl = &T[r * 132 + cg * 16];
#pragma unroll
    for (int k = 0; k < 4; ++k)
      *(float4*)(dst + k * 4) = *(const float4*)(srcl + k * 4);
  }
}

// ---------------- Kernel 4: out = ELU( sum_c num / sum_c den ) -------------
__global__ __launch_bounds__(256) void gat_fin(
    const float* __restrict__ num_part, const float* __restrict__ den_part,
    float* __restrict__ outp)
{
  const int flat = blockIdx.x * 256 + threadIdx.x;  // i*128+hf
  const int i = flat >> 7, hf = flat & 127, hh = hf >> 5;
  float s = 0.f, d = 0.f;
#pragma unroll
  for (int c = 0; c < 16; ++c) {
    s += num_part[(size_t)c * (N_NODES * OUT_F) + flat];
    d += den_part[((size_t)c * N_HEADS + hh) * N_NODES + i];
  }
  const float v = s / d;
  outp[flat] = v > 0.f ? v : expm1f(v);
}

extern "C" void kernel_launch(void* const* d_in, const int* in_sizes, int n_in,
                              void* d_out, int out_size, void* d_ws, size_t ws_size,
                              hipStream_t stream) {
  const float* hmat  = (const float*)d_in[0];
  const int*   adj   = (const int*)d_in[1];
  const float* Wl    = (const float*)d_in[2];
  const float* Wr    = (const float*)d_in[3];
  const float* attnw = (const float*)d_in[4];
  float* outp = (float*)d_out;

  char* ws = (char*)d_ws;
  float* gpart = (float*)(ws);                               // 8 MB
  float* g     = (float*)(ws + (8u << 20));                  // 1 MB
  float* abuf  = (float*)(ws + (9u << 20));                  // 16 KB
  float* bbuf  = (float*)(ws + (9u << 20) + (64u << 10));    // 16 KB
  unsigned long long* bits =
      (unsigned long long*)(ws + (9u << 20) + (128u << 10)); // 128 KB
  float* denp  = (float*)(ws + (9u << 20) + (256u << 10));   // 256 KB
  float* nump  = (float*)(ws + (10u << 20));                 // 8 MB

  gat_pack<<<1024, 256, 0, stream>>>(adj, bits);
  gat_gemm<<<512, 256, 0, stream>>>(hmat, Wl, Wr, gpart);
  gat_reduceWab<<<256, 256, 0, stream>>>(gpart, attnw, g, abuf, bbuf);
  gat_fused<<<512, 256, 0, stream>>>(g, attnw, abuf, bbuf, bits, nump, denp);
  gat_fin<<<512, 256, 0, stream>>>(nump, denp, outp);
}

// Round 8
// 103.519 us; speedup vs baseline: 1.4215x; 1.4215x over previous
//
#include <hip/hip_runtime.h>
#include <math.h>

#define N_NODES 1024
#define IN_F 512
#define N_HEADS 4
#define N_HID 32
#define OUT_F 128   // N_HEADS*N_HID
#define GF 256      // fused g row: [0..127]=g_l, [128..255]=g_r
#define NEG_SLOPE 0.2f

// ---------------- Kernel 0: pack adj into per-row bitmasks -----------------
// bits[i][w] bit k  <=>  adj[i][w*64+k] != 0.  1024 blocks x 256 thr.
__global__ __launch_bounds__(256) void gat_pack(
    const int* __restrict__ adj, unsigned long long* __restrict__ bits)
{
  const int i = blockIdx.x;
  const int t = threadIdx.x;
#pragma unroll
  for (int q = 0; q < 4; ++q) {
    const int j = q * 256 + t;
    const int a = adj[(size_t)i * N_NODES + j];
    const unsigned long long m = __ballot(a != 0);
    if ((t & 63) == 0) bits[i * 16 + (j >> 6)] = m;
  }
}

// ---------------- Kernel 1: LDS-tiled partial GEMM gpart[kc][row][c] -------
// grid 512 = (it 16 x ct 4 x kc 8), 256 thr. BM=BN=64, k-chunk 64, TK=16.
__global__ __launch_bounds__(256, 2) void gat_gemm(
    const float* __restrict__ hmat, const float* __restrict__ Wl,
    const float* __restrict__ Wr, float* __restrict__ gpart)
{
  const int b = blockIdx.x;
  const int kc = b & 7, ct = (b >> 3) & 3, it = b >> 5;
  const int i0 = it * 64, k0 = kc * 64, cb0 = ct * 64;
  const float* __restrict__ W = (cb0 < 128) ? (Wl + cb0) : (Wr + (cb0 - 128));

  __shared__ float As[16][68];
  __shared__ float Bs[16][64];

  const int tx = threadIdx.x & 15, ty = threadIdx.x >> 4;
  const int ar = threadIdx.x >> 2, ak = (threadIdx.x & 3) * 4;
  const int bk = threadIdx.x >> 4, bc = (threadIdx.x & 15) * 4;

  float4 acc0 = {0.f, 0.f, 0.f, 0.f}, acc1 = acc0, acc2 = acc0, acc3 = acc0;

  float4 av = *(const float4*)(hmat + (size_t)(i0 + ar) * IN_F + k0 + ak);
  float4 bv = *(const float4*)(W + (size_t)(k0 + bk) * OUT_F + bc);

  for (int t = 0; t < 64; t += 16) {
    __syncthreads();
    As[ak + 0][ar] = av.x; As[ak + 1][ar] = av.y;
    As[ak + 2][ar] = av.z; As[ak + 3][ar] = av.w;
    *(float4*)&Bs[bk][bc] = bv;
    __syncthreads();
    if (t < 48) {
      av = *(const float4*)(hmat + (size_t)(i0 + ar) * IN_F + k0 + t + 16 + ak);
      bv = *(const float4*)(W + (size_t)(k0 + t + 16 + bk) * OUT_F + bc);
    }
#pragma unroll
    for (int k = 0; k < 16; ++k) {
      const float4 a  = *(const float4*)&As[k][ty * 4];
      const float4 bb = *(const float4*)&Bs[k][tx * 4];
      acc0.x = fmaf(a.x, bb.x, acc0.x); acc0.y = fmaf(a.x, bb.y, acc0.y);
      acc0.z = fmaf(a.x, bb.z, acc0.z); acc0.w = fmaf(a.x, bb.w, acc0.w);
      acc1.x = fmaf(a.y, bb.x, acc1.x); acc1.y = fmaf(a.y, bb.y, acc1.y);
      acc1.z = fmaf(a.y, bb.z, acc1.z); acc1.w = fmaf(a.y, bb.w, acc1.w);
      acc2.x = fmaf(a.z, bb.x, acc2.x); acc2.y = fmaf(a.z, bb.y, acc2.y);
      acc2.z = fmaf(a.z, bb.z, acc2.z); acc2.w = fmaf(a.z, bb.w, acc2.w);
      acc3.x = fmaf(a.w, bb.x, acc3.x); acc3.y = fmaf(a.w, bb.y, acc3.y);
      acc3.z = fmaf(a.w, bb.z, acc3.z); acc3.w = fmaf(a.w, bb.w, acc3.w);
    }
  }
  const size_t rbase = (size_t)kc * N_NODES + i0 + ty * 4;
  const int cc = cb0 + tx * 4;
  *(float4*)(gpart + (rbase + 0) * GF + cc) = acc0;
  *(float4*)(gpart + (rbase + 1) * GF + cc) = acc1;
  *(float4*)(gpart + (rbase + 2) * GF + cc) = acc2;
  *(float4*)(gpart + (rbase + 3) * GF + cc) = acc3;
}

// ---------------- Kernel 2: g = sum partials; alpha/beta precompute --------
__global__ __launch_bounds__(256) void gat_reduceWab(
    const float* __restrict__ gpart, const float* __restrict__ attn_w,
    float* __restrict__ g, float* __restrict__ abuf, float* __restrict__ bbuf)
{
  const int tid = threadIdx.x;
  const int l = tid & 63, r = tid >> 6;
  const int row = blockIdx.x * 4 + r;
  const size_t o = (size_t)row * GF + l * 4;
  float4 s = *(const float4*)(gpart + o);
#pragma unroll
  for (int c = 1; c < 8; ++c) {
    const float4 v = *(const float4*)(gpart + (size_t)c * (N_NODES * GF) + o);
    s.x += v.x; s.y += v.y; s.z += v.z; s.w += v.w;
  }
  *(float4*)(g + o) = s;
  const float4 a4 = *(const float4*)(attn_w + (l & 7) * 4);
  float d = 0.6f * (s.x * a4.x + s.y * a4.y + s.z * a4.z + s.w * a4.w);
  d += __shfl_xor(d, 1);
  d += __shfl_xor(d, 2);
  d += __shfl_xor(d, 4);
  if ((l & 7) == 0) {
    const int hq = l >> 3;  // 0-3 -> alpha (gl), 4-7 -> beta (gr)
    if (hq < 4) abuf[hq * N_NODES + row] = d;
    else        bbuf[(hq - 4) * N_NODES + row] = d;
  }
}

// ---------------- Kernel 3: fused score + aggregate (p stays in LDS) -------
// grid 512 = (jc 16 x it 32); block = 32 i x 64 j (2 subtiles of 32) x 4 h.
// Per subtile: phase1 (wave=head, lane=half|il): score -> ps[j][h][i];
//              phase2 (thread = 4i x 4f tile): num += ps * gr  from LDS.
// Persistent regs ~75 (gri 16 + c2 16 + num 16 + misc) -> no spill at 128 cap.
__global__ __launch_bounds__(256, 2) void gat_fused(
    const float* __restrict__ g, const float* __restrict__ attn_w,
    const float* __restrict__ abuf, const float* __restrict__ bbuf,
    const unsigned long long* __restrict__ bits,
    float* __restrict__ num_part, float* __restrict__ den_part)
{
  __shared__ float gj[32][256];     // j-subtile rows of fused g (gl|gr), 32 KB
  __shared__ float ps[32][4][36];   // p[j][h][i], padded: 16B-aligned, 18.4 KB
  __shared__ float as_[4][32];      // alpha tile

  const int b = blockIdx.x;
  const int jc = b & 15, it = b >> 4;
  const int i0 = it * 32, j0 = jc * 64;
  const int t = threadIdx.x;

  // phase-1 mapping: wave = head; lane = half(1b)|il(5b)
  const int hh = t >> 6, half = (t >> 5) & 1, il = t & 31;
  const int i = i0 + il;
  const int fb1 = hh * N_HID + half * 16;

  // phase-2 mapping: thread = (ig 3b | h2 2b | fg 3b); 4 i x 4 f tile
  const int ig = t >> 5, h2 = (t >> 3) & 3, fg = t & 7;

  // staging mapping: wave wv stages rows wv*8..+7, lane ln covers float4 ln
  const int wv = t >> 6, ln = t & 63;

  float4 gri[4], c2[4], num[4];
#pragma unroll
  for (int q = 0; q < 4; ++q) {
    gri[q] = *(const float4*)(g + (size_t)i * GF + 128 + fb1 + q * 4);
    const float4 a4 = *(const float4*)(attn_w + half * 16 + q * 4);
    c2[q] = make_float4(0.4f * a4.x, 0.4f * a4.y, 0.4f * a4.z, 0.4f * a4.w);
    num[q] = make_float4(0.f, 0.f, 0.f, 0.f);
  }
  const float beta = bbuf[hh * N_NODES + i];
  const unsigned long long bm = bits[(size_t)i * 16 + jc];
  float den_t = 0.f;

  for (int ts = 0; ts < 2; ++ts) {
    __syncthreads();
    // stage 32 j-rows: one full row per wave-instruction (coalesced global,
    // conflict-free LDS: 64 lanes cover 1KB contiguous)
#pragma unroll
    for (int k = 0; k < 8; ++k) {
      const int r = wv * 8 + k;
      *(float4*)&gj[r][ln * 4] =
          *(const float4*)(g + (size_t)(j0 + ts * 32 + r) * GF + ln * 4);
    }
    if (t < 128)
      as_[t >> 5][t & 31] =
          abuf[(t >> 5) * N_NODES + j0 + ts * 32 + (t & 31)];
    __syncthreads();

    // ---- phase 1: scores into ps -------------------------------------
    const unsigned int w32 = (unsigned int)(bm >> (ts * 32));
#pragma unroll 4
    for (int j = 0; j < 32; ++j) {
      float part = 0.f;
#pragma unroll
      for (int q = 0; q < 4; ++q) {
        const float4 gl = *(const float4*)&gj[j][fb1 + q * 4];  // 2-addr bcast
        float s;
        s = gl.x + gri[q].x; part = fmaf(c2[q].x, __builtin_fabsf(s), part);
        s = gl.y + gri[q].y; part = fmaf(c2[q].y, __builtin_fabsf(s), part);
        s = gl.z + gri[q].z; part = fmaf(c2[q].z, __builtin_fabsf(s), part);
        s = gl.w + gri[q].w; part = fmaf(c2[q].w, __builtin_fabsf(s), part);
      }
      const float full = part + __shfl_xor(part, 32);  // combine halves
      const float e = full + as_[hh][j] + beta;
      const float p = ((w32 >> j) & 1u) ? __expf(e) : 0.f;
      if (half == 0) ps[j][hh][il] = p;  // 32 consecutive floats: no conflict
      den_t += p;
    }
    __syncthreads();

    // ---- phase 2: num += ps * gr -------------------------------------
#pragma unroll 4
    for (int j = 0; j < 32; ++j) {
      const float4 pv = *(const float4*)&ps[j][h2][ig * 4];          // 4 i's
      const float4 gv = *(const float4*)&gj[j][128 + h2 * 32 + fg * 4];  // 4 f's
      num[0].x = fmaf(pv.x, gv.x, num[0].x);
      num[0].y = fmaf(pv.x, gv.y, num[0].y);
      num[0].z = fmaf(pv.x, gv.z, num[0].z);
      num[0].w = fmaf(pv.x, gv.w, num[0].w);
      num[1].x = fmaf(pv.y, gv.x, num[1].x);
      num[1].y = fmaf(pv.y, gv.y, num[1].y);
      num[1].z = fmaf(pv.y, gv.z, num[1].z);
      num[1].w = fmaf(pv.y, gv.w, num[1].w);
      num[2].x = fmaf(pv.z, gv.x, num[2].x);
      num[2].y = fmaf(pv.z, gv.y, num[2].y);
      num[2].z = fmaf(pv.z, gv.z, num[2].z);
      num[2].w = fmaf(pv.z, gv.w, num[2].w);
      num[3].x = fmaf(pv.w, gv.x, num[3].x);
      num[3].y = fmaf(pv.w, gv.y, num[3].y);
      num[3].z = fmaf(pv.w, gv.z, num[3].z);
      num[3].w = fmaf(pv.w, gv.w, num[3].w);
    }
  }

  // epilogue: den (lane-local, only half0's copy) + num partials
  if (half == 0)
    den_part[((size_t)jc * N_HEADS + hh) * N_NODES + i] = den_t;
  float* np = num_part + ((size_t)jc * N_NODES + i0 + ig * 4) * OUT_F +
              h2 * N_HID + fg * 4;
#pragma unroll
  for (int ii = 0; ii < 4; ++ii) {
    const float4 v = num[ii];
    *(float4*)(np + (size_t)ii * OUT_F) = v;
  }
}

// ---------------- Kernel 4: out = ELU( sum_c num / sum_c den ) -------------
__global__ __launch_bounds__(256) void gat_fin(
    const float* __restrict__ num_part, const float* __restrict__ den_part,
    float* __restrict__ outp)
{
  const int flat = blockIdx.x * 256 + threadIdx.x;  // i*128+hf
  const int i = flat >> 7, hf = flat & 127, hh = hf >> 5;
  float s = 0.f, d = 0.f;
#pragma unroll
  for (int c = 0; c < 16; ++c) {
    s += num_part[(size_t)c * (N_NODES * OUT_F) + flat];
    d += den_part[((size_t)c * N_HEADS + hh) * N_NODES + i];
  }
  const float v = s / d;
  outp[flat] = v > 0.f ? v : expm1f(v);
}

extern "C" void kernel_launch(void* const* d_in, const int* in_sizes, int n_in,
                              void* d_out, int out_size, void* d_ws, size_t ws_size,
                              hipStream_t stream) {
  const float* hmat  = (const float*)d_in[0];
  const int*   adj   = (const int*)d_in[1];
  const float* Wl    = (const float*)d_in[2];
  const float* Wr    = (const float*)d_in[3];
  const float* attnw = (const float*)d_in[4];
  float* outp = (float*)d_out;

  char* ws = (char*)d_ws;
  float* gpart = (float*)(ws);                               // 8 MB
  float* g     = (float*)(ws + (8u << 20));                  // 1 MB
  float* abuf  = (float*)(ws + (9u << 20));                  // 16 KB
  float* bbuf  = (float*)(ws + (9u << 20) + (64u << 10));    // 16 KB
  unsigned long long* bits =
      (unsigned long long*)(ws + (9u << 20) + (128u << 10)); // 128 KB
  float* denp  = (float*)(ws + (9u << 20) + (256u << 10));   // 256 KB
  float* nump  = (float*)(ws + (10u << 20));                 // 8 MB

  gat_pack<<<1024, 256, 0, stream>>>(adj, bits);
  gat_gemm<<<512, 256, 0, stream>>>(hmat, Wl, Wr, gpart);
  gat_reduceWab<<<256, 256, 0, stream>>>(gpart, attnw, g, abuf, bbuf);
  gat_fused<<<512, 256, 0, stream>>>(g, attnw, abuf, bbuf, bits, nump, denp);
  gat_fin<<<512, 256, 0, stream>>>(nump, denp, outp);
}

// Round 9
// 101.545 us; speedup vs baseline: 1.4491x; 1.0194x over previous
//
#include <hip/hip_runtime.h>
#include <math.h>

#define N_NODES 1024
#define IN_F 512
#define N_HEADS 4
#define N_HID 32
#define OUT_F 128   // N_HEADS*N_HID
#define GF 256      // fused g row: [0..127]=g_l, [128..255]=g_r
#define NEG_SLOPE 0.2f

// ---------------- Kernel 1: LDS-tiled partial GEMM + adj bit-pack ----------
// grid 512 = (it 16 x ct 4 x kc 8), 256 thr. BM=BN=64, k-chunk 64, TK=16.
// Tail: each block packs adj rows 2b, 2b+1 into 64-bit masks (independent
// work; bits consumed two launches later by gat_fused).
__global__ __launch_bounds__(256, 2) void gat_gemm(
    const float* __restrict__ hmat, const float* __restrict__ Wl,
    const float* __restrict__ Wr, const int* __restrict__ adj,
    float* __restrict__ gpart, unsigned long long* __restrict__ bits)
{
  const int b = blockIdx.x;
  const int kc = b & 7, ct = (b >> 3) & 3, it = b >> 5;
  const int i0 = it * 64, k0 = kc * 64, cb0 = ct * 64;
  const float* __restrict__ W = (cb0 < 128) ? (Wl + cb0) : (Wr + (cb0 - 128));

  __shared__ float As[16][68];
  __shared__ float Bs[16][64];

  const int tx = threadIdx.x & 15, ty = threadIdx.x >> 4;
  const int ar = threadIdx.x >> 2, ak = (threadIdx.x & 3) * 4;
  const int bk = threadIdx.x >> 4, bc = (threadIdx.x & 15) * 4;

  float4 acc0 = {0.f, 0.f, 0.f, 0.f}, acc1 = acc0, acc2 = acc0, acc3 = acc0;

  float4 av = *(const float4*)(hmat + (size_t)(i0 + ar) * IN_F + k0 + ak);
  float4 bv = *(const float4*)(W + (size_t)(k0 + bk) * OUT_F + bc);

  for (int t = 0; t < 64; t += 16) {
    __syncthreads();
    As[ak + 0][ar] = av.x; As[ak + 1][ar] = av.y;
    As[ak + 2][ar] = av.z; As[ak + 3][ar] = av.w;
    *(float4*)&Bs[bk][bc] = bv;
    __syncthreads();
    if (t < 48) {
      av = *(const float4*)(hmat + (size_t)(i0 + ar) * IN_F + k0 + t + 16 + ak);
      bv = *(const float4*)(W + (size_t)(k0 + t + 16 + bk) * OUT_F + bc);
    }
#pragma unroll
    for (int k = 0; k < 16; ++k) {
      const float4 a  = *(const float4*)&As[k][ty * 4];
      const float4 bb = *(const float4*)&Bs[k][tx * 4];
      acc0.x = fmaf(a.x, bb.x, acc0.x); acc0.y = fmaf(a.x, bb.y, acc0.y);
      acc0.z = fmaf(a.x, bb.z, acc0.z); acc0.w = fmaf(a.x, bb.w, acc0.w);
      acc1.x = fmaf(a.y, bb.x, acc1.x); acc1.y = fmaf(a.y, bb.y, acc1.y);
      acc1.z = fmaf(a.y, bb.z, acc1.z); acc1.w = fmaf(a.y, bb.w, acc1.w);
      acc2.x = fmaf(a.z, bb.x, acc2.x); acc2.y = fmaf(a.z, bb.y, acc2.y);
      acc2.z = fmaf(a.z, bb.z, acc2.z); acc2.w = fmaf(a.z, bb.w, acc2.w);
      acc3.x = fmaf(a.w, bb.x, acc3.x); acc3.y = fmaf(a.w, bb.y, acc3.y);
      acc3.z = fmaf(a.w, bb.z, acc3.z); acc3.w = fmaf(a.w, bb.w, acc3.w);
    }
  }
  const size_t rbase = (size_t)kc * N_NODES + i0 + ty * 4;
  const int cc = cb0 + tx * 4;
  *(float4*)(gpart + (rbase + 0) * GF + cc) = acc0;
  *(float4*)(gpart + (rbase + 1) * GF + cc) = acc1;
  *(float4*)(gpart + (rbase + 2) * GF + cc) = acc2;
  *(float4*)(gpart + (rbase + 3) * GF + cc) = acc3;

  // ---- adj bit-pack tail: rows 2b, 2b+1 ----
#pragma unroll
  for (int r = 0; r < 2; ++r) {
    const int i = b * 2 + r;
#pragma unroll
    for (int q = 0; q < 4; ++q) {
      const int j = q * 256 + threadIdx.x;
      const unsigned long long m =
          __ballot(adj[(size_t)i * N_NODES + j] != 0);
      if ((threadIdx.x & 63) == 0) bits[i * 16 + (j >> 6)] = m;
    }
  }
}

// ---------------- Kernel 2: g = sum partials; alpha/beta precompute --------
__global__ __launch_bounds__(256) void gat_reduceWab(
    const float* __restrict__ gpart, const float* __restrict__ attn_w,
    float* __restrict__ g, float* __restrict__ abuf, float* __restrict__ bbuf)
{
  const int tid = threadIdx.x;
  const int l = tid & 63, r = tid >> 6;
  const int row = blockIdx.x * 4 + r;
  const size_t o = (size_t)row * GF + l * 4;
  float4 s = *(const float4*)(gpart + o);
#pragma unroll
  for (int c = 1; c < 8; ++c) {
    const float4 v = *(const float4*)(gpart + (size_t)c * (N_NODES * GF) + o);
    s.x += v.x; s.y += v.y; s.z += v.z; s.w += v.w;
  }
  *(float4*)(g + o) = s;
  const float4 a4 = *(const float4*)(attn_w + (l & 7) * 4);
  float d = 0.6f * (s.x * a4.x + s.y * a4.y + s.z * a4.z + s.w * a4.w);
  d += __shfl_xor(d, 1);
  d += __shfl_xor(d, 2);
  d += __shfl_xor(d, 4);
  if ((l & 7) == 0) {
    const int hq = l >> 3;  // 0-3 -> alpha (gl), 4-7 -> beta (gr)
    if (hq < 4) abuf[hq * N_NODES + row] = d;
    else        bbuf[(hq - 4) * N_NODES + row] = d;
  }
}

// ---------------- Kernel 3: fused score + aggregate (p stays in LDS) -------
// grid 512 = (jc 16 x it 32); block = 32 i x 64 j (2 subtiles of 32) x 4 h.
// Per subtile: phase1 (wave=head, lane=half|il): score -> ps[j][h][i];
//              phase2 (thread = 4i x 4f tile): num += ps * gr  from LDS.
__global__ __launch_bounds__(256, 2) void gat_fused(
    const float* __restrict__ g, const float* __restrict__ attn_w,
    const float* __restrict__ abuf, const float* __restrict__ bbuf,
    const unsigned long long* __restrict__ bits,
    float* __restrict__ num_part, float* __restrict__ den_part)
{
  __shared__ float gj[32][256];     // j-subtile rows of fused g (gl|gr), 32 KB
  __shared__ float ps[32][4][36];   // p[j][h][i], padded: 16B-aligned, 18.4 KB
  __shared__ float as_[4][32];      // alpha tile

  const int b = blockIdx.x;
  const int jc = b & 15, it = b >> 4;
  const int i0 = it * 32, j0 = jc * 64;
  const int t = threadIdx.x;

  // phase-1 mapping: wave = head; lane = half(1b)|il(5b)
  const int hh = t >> 6, half = (t >> 5) & 1, il = t & 31;
  const int i = i0 + il;
  const int fb1 = hh * N_HID + half * 16;

  // phase-2 mapping: thread = (ig 3b | h2 2b | fg 3b); 4 i x 4 f tile
  const int ig = t >> 5, h2 = (t >> 3) & 3, fg = t & 7;

  // staging mapping: wave wv stages rows wv*8..+7, lane ln covers float4 ln
  const int wv = t >> 6, ln = t & 63;

  float4 gri[4], c2[4], num[4];
#pragma unroll
  for (int q = 0; q < 4; ++q) {
    gri[q] = *(const float4*)(g + (size_t)i * GF + 128 + fb1 + q * 4);
    const float4 a4 = *(const float4*)(attn_w + half * 16 + q * 4);
    c2[q] = make_float4(0.4f * a4.x, 0.4f * a4.y, 0.4f * a4.z, 0.4f * a4.w);
    num[q] = make_float4(0.f, 0.f, 0.f, 0.f);
  }
  const float beta = bbuf[hh * N_NODES + i];
  const unsigned long long bm = bits[(size_t)i * 16 + jc];
  float den_t = 0.f;

  for (int ts = 0; ts < 2; ++ts) {
    __syncthreads();
#pragma unroll
    for (int k = 0; k < 8; ++k) {
      const int r = wv * 8 + k;
      *(float4*)&gj[r][ln * 4] =
          *(const float4*)(g + (size_t)(j0 + ts * 32 + r) * GF + ln * 4);
    }
    if (t < 128)
      as_[t >> 5][t & 31] =
          abuf[(t >> 5) * N_NODES + j0 + ts * 32 + (t & 31)];
    __syncthreads();

    // ---- phase 1: scores into ps -------------------------------------
    const unsigned int w32 = (unsigned int)(bm >> (ts * 32));
#pragma unroll 4
    for (int j = 0; j < 32; ++j) {
      float part = 0.f;
#pragma unroll
      for (int q = 0; q < 4; ++q) {
        const float4 gl = *(const float4*)&gj[j][fb1 + q * 4];  // 2-addr bcast
        float s;
        s = gl.x + gri[q].x; part = fmaf(c2[q].x, __builtin_fabsf(s), part);
        s = gl.y + gri[q].y; part = fmaf(c2[q].y, __builtin_fabsf(s), part);
        s = gl.z + gri[q].z; part = fmaf(c2[q].z, __builtin_fabsf(s), part);
        s = gl.w + gri[q].w; part = fmaf(c2[q].w, __builtin_fabsf(s), part);
      }
      const float full = part + __shfl_xor(part, 32);  // combine halves
      const float e = full + as_[hh][j] + beta;
      const float p = ((w32 >> j) & 1u) ? __expf(e) : 0.f;
      if (half == 0) ps[j][hh][il] = p;  // 32 consecutive floats: no conflict
      den_t += p;
    }
    __syncthreads();

    // ---- phase 2: num += ps * gr -------------------------------------
#pragma unroll 4
    for (int j = 0; j < 32; ++j) {
      const float4 pv = *(const float4*)&ps[j][h2][ig * 4];          // 4 i's
      const float4 gv = *(const float4*)&gj[j][128 + h2 * 32 + fg * 4];  // 4 f's
      num[0].x = fmaf(pv.x, gv.x, num[0].x);
      num[0].y = fmaf(pv.x, gv.y, num[0].y);
      num[0].z = fmaf(pv.x, gv.z, num[0].z);
      num[0].w = fmaf(pv.x, gv.w, num[0].w);
      num[1].x = fmaf(pv.y, gv.x, num[1].x);
      num[1].y = fmaf(pv.y, gv.y, num[1].y);
      num[1].z = fmaf(pv.y, gv.z, num[1].z);
      num[1].w = fmaf(pv.y, gv.w, num[1].w);
      num[2].x = fmaf(pv.z, gv.x, num[2].x);
      num[2].y = fmaf(pv.z, gv.y, num[2].y);
      num[2].z = fmaf(pv.z, gv.z, num[2].z);
      num[2].w = fmaf(pv.z, gv.w, num[2].w);
      num[3].x = fmaf(pv.w, gv.x, num[3].x);
      num[3].y = fmaf(pv.w, gv.y, num[3].y);
      num[3].z = fmaf(pv.w, gv.z, num[3].z);
      num[3].w = fmaf(pv.w, gv.w, num[3].w);
    }
  }

  if (half == 0)
    den_part[((size_t)jc * N_HEADS + hh) * N_NODES + i] = den_t;
  float* np = num_part + ((size_t)jc * N_NODES + i0 + ig * 4) * OUT_F +
              h2 * N_HID + fg * 4;
#pragma unroll
  for (int ii = 0; ii < 4; ++ii) {
    const float4 v = num[ii];
    *(float4*)(np + (size_t)ii * OUT_F) = v;
  }
}

// ---------------- Kernel 4: out = ELU( sum_c num / sum_c den ), float4 -----
// 128 blocks x 256 thr; thread = 4 consecutive hf of one (i, head).
__global__ __launch_bounds__(256) void gat_fin(
    const float* __restrict__ num_part, const float* __restrict__ den_part,
    float* __restrict__ outp)
{
  const int e4 = blockIdx.x * 256 + threadIdx.x;  // float4 index, 32768 total
  const int flat = e4 * 4;
  const int i = flat >> 7, hh = (flat & 127) >> 5;
  float4 s = {0.f, 0.f, 0.f, 0.f};
  float d = 0.f;
#pragma unroll
  for (int c = 0; c < 16; ++c) {
    const float4 v = *(const float4*)(num_part + (size_t)c * (N_NODES * OUT_F) + flat);
    s.x += v.x; s.y += v.y; s.z += v.z; s.w += v.w;
    d += den_part[((size_t)c * N_HEADS + hh) * N_NODES + i];
  }
  const float inv = 1.0f / d;
  float4 o;
  o.x = s.x * inv; o.y = s.y * inv; o.z = s.z * inv; o.w = s.w * inv;
  o.x = o.x > 0.f ? o.x : expm1f(o.x);
  o.y = o.y > 0.f ? o.y : expm1f(o.y);
  o.z = o.z > 0.f ? o.z : expm1f(o.z);
  o.w = o.w > 0.f ? o.w : expm1f(o.w);
  *(float4*)(outp + flat) = o;
}

extern "C" void kernel_launch(void* const* d_in, const int* in_sizes, int n_in,
                              void* d_out, int out_size, void* d_ws, size_t ws_size,
                              hipStream_t stream) {
  const float* hmat  = (const float*)d_in[0];
  const int*   adj   = (const int*)d_in[1];
  const float* Wl    = (const float*)d_in[2];
  const float* Wr    = (const float*)d_in[3];
  const float* attnw = (const float*)d_in[4];
  float* outp = (float*)d_out;

  char* ws = (char*)d_ws;
  float* gpart = (float*)(ws);                               // 8 MB
  float* g     = (float*)(ws + (8u << 20));                  // 1 MB
  float* abuf  = (float*)(ws + (9u << 20));                  // 16 KB
  float* bbuf  = (float*)(ws + (9u << 20) + (64u << 10));    // 16 KB
  unsigned long long* bits =
      (unsigned long long*)(ws + (9u << 20) + (128u << 10)); // 128 KB
  float* denp  = (float*)(ws + (9u << 20) + (256u << 10));   // 256 KB
  float* nump  = (float*)(ws + (10u << 20));                 // 8 MB

  gat_gemm<<<512, 256, 0, stream>>>(hmat, Wl, Wr, adj, gpart, bits);
  gat_reduceWab<<<256, 256, 0, stream>>>(gpart, attnw, g, abuf, bbuf);
  gat_fused<<<512, 256, 0, stream>>>(g, attnw, abuf, bbuf, bits, nump, denp);
  gat_fin<<<128, 256, 0, stream>>>(nump, denp, outp);
}